// Round 3
// baseline (114.445 us; speedup 1.0000x reference)
//
#include <hip/hip_runtime.h>

// ---- types ----------------------------------------------------------------
typedef __attribute__((ext_vector_type(8))) short bf16x8;     // 8 bf16 (4 VGPR)
typedef __attribute__((ext_vector_type(4))) float f32x4;
typedef __attribute__((ext_vector_type(4))) unsigned short us4;
typedef __attribute__((ext_vector_type(8))) unsigned short us8;

#define MFMA(a, b, c) __builtin_amdgcn_mfma_f32_16x16x32_bf16((a), (b), (c), 0, 0, 0)

__device__ __forceinline__ unsigned short f2bf(float f) {
  unsigned u = __builtin_bit_cast(unsigned, f);
  u = (u + 0x7fffu + ((u >> 16) & 1u)) >> 16;  // RNE
  return (unsigned short)u;
}

__device__ __forceinline__ void gload16(const void* g, void* l) {
  __builtin_amdgcn_global_load_lds((const __attribute__((address_space(1))) void*)g,
                                   (__attribute__((address_space(3))) void*)l,
                                   16, 0, 0);
}

// swizzled fragment read: rows are 128B apart; phys = byte ^ ((row&7)<<4)
__device__ __forceinline__ bf16x8 readfrag(const unsigned short* buf, int row, int kbyte) {
  int byte = row * 128 + kbyte;
  byte ^= (row & 7) << 4;
  return *(const bf16x8*)((const char*)buf + byte);
}

// ---- kernel 1: cast x -> bf16 (float4 vectorized) --------------------------
__global__ void cast_x_kernel(const float* __restrict__ x,
                              unsigned short* __restrict__ xb, int n4) {
  int id = blockIdx.x * blockDim.x + threadIdx.x;
  if (id >= n4) return;
  float4 v = ((const float4*)x)[id];
  us4 o = { f2bf(v.x), f2bf(v.y), f2bf(v.z), f2bf(v.w) };
  ((us4*)xb)[id] = o;
}

// ---- kernel 2: W [768][2304] -> Wt [2304][768] bf16 (tiled transpose) ------
__global__ void castw_kernel(const float* __restrict__ W,
                             unsigned short* __restrict__ Wt) {
  __shared__ unsigned short tile[32][33];
  int bn = blockIdx.x * 32;
  int bk = blockIdx.y * 32;
  int lx = threadIdx.x & 31, ly = threadIdx.x >> 5;  // 32 x 8
#pragma unroll
  for (int i = 0; i < 32; i += 8)
    tile[ly + i][lx] = f2bf(W[(bk + ly + i) * 2304 + bn + lx]);
  __syncthreads();
#pragma unroll
  for (int i = 0; i < 32; i += 8)
    Wt[(bn + ly + i) * 768 + bk + lx] = tile[lx][ly + i];
}

// ---- kernel 3: QKV GEMM (pipelined, counted vmcnt) — unchanged from R2 -----
__global__ __launch_bounds__(512, 2) void qkv_gemm_kernel(
    const unsigned short* __restrict__ xb, const unsigned short* __restrict__ wt,
    const float* __restrict__ bias,
    unsigned short* __restrict__ qb, unsigned short* __restrict__ kb,
    unsigned short* __restrict__ vb) {
  __shared__ unsigned short lds[65536];  // 128 KB: A 3x16384 elems @0, B 2x8192 @49152
  const int tid = threadIdx.x;
  const int lane = tid & 63, wid = tid >> 6;
  const int wm = wid >> 1, wn = wid & 1;
  const int l15 = lane & 15, lg = lane >> 4;

  int bid = blockIdx.x;
  int xcd = bid & 7, c = bid >> 3;
  int mb = (xcd & 3) * 8 + (c & 7);
  int nb = (xcd >> 2) * 9 + (c >> 3);
  const int m0 = mb * 256, n0 = nb * 128;

  const unsigned short* Ab_g = xb + (size_t)m0 * 768;
  const unsigned short* Bb_g = wt + (size_t)n0 * 768;

  int eA[4], sA[4], eB[2], sB[2];
#pragma unroll
  for (int i = 0; i < 4; ++i) {
    int e = (i * 512 + tid) * 8, row = e >> 6;
    eA[i] = e;
    sA[i] = row * 768 + ((e ^ ((row & 7) << 3)) & 63);
  }
#pragma unroll
  for (int i = 0; i < 2; ++i) {
    int e = (i * 512 + tid) * 8, row = e >> 6;
    eB[i] = e;
    sB[i] = row * 768 + ((e ^ ((row & 7) << 3)) & 63);
  }

#define SA(buf, k0, i) gload16(Ab_g + sA[i] + (k0), &lds[(buf) * 16384 + eA[i]])
#define SB(buf, k0, i) gload16(Bb_g + sB[i] + (k0), &lds[49152 + (buf) * 8192 + eB[i]])

  f32x4 acc[4][4] = {};
  bf16x8 bfr[4][2];

  SA(0, 0, 0); SA(0, 0, 1); SA(0, 0, 2); SA(0, 0, 3);
  SB(0, 0, 0); SB(0, 0, 1);
  SA(1, 64, 0); SA(1, 64, 1); SA(1, 64, 2); SA(1, 64, 3);
  asm volatile("s_waitcnt vmcnt(4)" ::: "memory");
  __builtin_amdgcn_s_barrier();

#define GPHASE(cA_, cB_, Q, STG, EW)                                              \
  {                                                                               \
    const unsigned short* Abuf = &lds[(cA_) * 16384];                             \
    const unsigned short* Bbuf = &lds[49152 + (cB_) * 8192];                      \
    bf16x8 afr[2][2];                                                             \
    _Pragma("unroll") for (int m2 = 0; m2 < 2; ++m2)                              \
        _Pragma("unroll") for (int kk = 0; kk < 2; ++kk)                          \
            afr[m2][kk] =                                                         \
        readfrag(Abuf, wm * 64 + ((Q) * 2 + m2) * 16 + l15, kk * 64 + lg * 16);   \
    if ((Q) == 0) {                                                               \
      _Pragma("unroll") for (int nf = 0; nf < 4; ++nf)                            \
          _Pragma("unroll") for (int kk = 0; kk < 2; ++kk)                        \
              bfr[nf][kk] =                                                       \
          readfrag(Bbuf, wn * 64 + nf * 16 + l15, kk * 64 + lg * 16);             \
    }                                                                             \
    STG;                                                                          \
    __builtin_amdgcn_sched_barrier(0);                                            \
    __builtin_amdgcn_s_barrier();                                                 \
    asm volatile("s_waitcnt lgkmcnt(0)" ::: "memory");                            \
    __builtin_amdgcn_sched_barrier(0);                                            \
    __builtin_amdgcn_s_setprio(1);                                                \
    _Pragma("unroll") for (int m2 = 0; m2 < 2; ++m2)                              \
        _Pragma("unroll") for (int nf = 0; nf < 4; ++nf)                          \
            _Pragma("unroll") for (int kk = 0; kk < 2; ++kk)                      \
                acc[(Q) * 2 + m2][nf] =                                           \
        MFMA(afr[m2][kk], bfr[nf][kk], acc[(Q) * 2 + m2][nf]);                    \
    __builtin_amdgcn_s_setprio(0);                                                \
    EW;                                                                           \
    __builtin_amdgcn_sched_barrier(0);                                            \
    __builtin_amdgcn_s_barrier();                                                 \
  }

  int cA = 0;
  for (int kt = 0; kt < 10; ++kt) {
    int cB = kt & 1, cBn = cB ^ 1;
    int cA2 = cA + 2; if (cA2 >= 3) cA2 -= 3;
    int k1 = (kt + 1) * 64, k2 = (kt + 2) * 64;
    GPHASE(cA, cB, 0,
           { SB(cBn, k1, 0); SB(cBn, k1, 1); SA(cA2, k2, 0); SA(cA2, k2, 1); }, );
    GPHASE(cA, cB, 1, { SA(cA2, k2, 2); SA(cA2, k2, 3); },
           asm volatile("s_waitcnt vmcnt(4)" ::: "memory"));
    cA = (cA == 2) ? 0 : cA + 1;
  }
  GPHASE(cA, 0, 0, { SB(1, 704, 0); SB(1, 704, 1); }, );
  GPHASE(cA, 0, 1, ,
         asm volatile("s_waitcnt vmcnt(0)" ::: "memory"));
  cA = (cA == 2) ? 0 : cA + 1;
  GPHASE(cA, 1, 0, , );
  GPHASE(cA, 1, 1, , );

  __syncthreads();

  const int sec = n0 / 768;
  float bcol[4];
#pragma unroll
  for (int nf = 0; nf < 4; ++nf) bcol[nf] = bias[n0 + wn * 64 + nf * 16 + l15];

  if (sec < 2) {
    unsigned short* ct = lds;  // [256][128]
#pragma unroll
    for (int mf = 0; mf < 4; ++mf)
#pragma unroll
      for (int nf = 0; nf < 4; ++nf)
#pragma unroll
        for (int r = 0; r < 4; ++r)
          ct[(wm * 64 + mf * 16 + lg * 4 + r) * 128 + wn * 64 + nf * 16 + l15] =
              f2bf(acc[mf][nf][r] + bcol[nf]);
    __syncthreads();
    unsigned short* dstbase = (sec == 0) ? qb : kb;
    const int hbase = (n0 - sec * 768) >> 6;
    const int g8 = tid >> 3, l8 = tid & 7;
#pragma unroll
    for (int j = 0; j < 8; ++j) {
      int chunk = j * 64 + g8;
      int row = chunk >> 1, hh = chunk & 1;
      us8 v = *(const us8*)&ct[row * 128 + hh * 64 + l8 * 8];
      int t = m0 + row, bb = t >> 10, tt = t & 1023;
      *(us8*)(dstbase + ((size_t)((bb * 12 + hbase + hh) * 1024 + tt)) * 64 + l8 * 8) = v;
    }
  } else {
#pragma unroll
    for (int nf = 0; nf < 4; ++nf) {
      int cc = (n0 - 1536) + wn * 64 + nf * 16 + l15;
      int h = cc >> 6, d = cc & 63;
#pragma unroll
      for (int mf = 0; mf < 4; ++mf) {
        int row0 = m0 + wm * 64 + mf * 16 + lg * 4;
        int bb = row0 >> 10, t0 = row0 & 1023;
        us4 o;
#pragma unroll
        for (int r = 0; r < 4; ++r) o[r] = f2bf(acc[mf][nf][r] + bcol[nf]);
        *(us4*)(vb + ((size_t)((bb * 12 + h) * 64 + d)) * 1024 + t0) = o;
      }
    }
  }
#undef SA
#undef SB
#undef GPHASE
}

// ---- kernel 4: causal ReLU attention, GEMM-shaped --------------------------
// block = (b,h) x 256 q-rows. 8 waves = 4 q-subtiles x 2 k-streams.
// k-tiles are independent (no softmax state) -> pure accumulation, 2-stream
// split over kt parity; wave-private S (no QK->PV barrier); dbuf K/V staging.
__global__ __launch_bounds__(512) void attn_kernel(
    const unsigned short* __restrict__ qb, const unsigned short* __restrict__ kb,
    const unsigned short* __restrict__ vb, float* __restrict__ out) {
  // LDS elems: K [buf][stream][4096] @0..16384, V @16384..32768,
  //            S per-wave 4096 @32768+wid*4096. Total 65536 elems = 128KB.
  __shared__ unsigned short lds[65536];
  const int tid = threadIdx.x;
  const int lane = tid & 63, wid = tid >> 6;
  const int qs = wid >> 1, ks = wid & 1;
  const int l15 = lane & 15, lg = lane >> 4;

  // XCD swizzle: 384 blocks = 8 XCDs x 48; each XCD owns 12 bh (K/V 3MB in L2).
  // heavy q-blocks (byq=3) dispatched first.
  int bid = blockIdx.x;
  int xcd = bid & 7, c = bid >> 3;       // c 0..47
  int bh = xcd * 12 + (c % 12);
  int byq = 3 - (c / 12);
  const int b = bh / 12, h = bh % 12;
  const size_t base = (size_t)bh * 65536;
  const int Q = byq * 4 + qs;            // wave's global q-tile index
  const int qr0 = byq * 256 + qs * 64;   // wave's global q-row base

  // Q fragments in registers (A-operand: lane l15 = q-row, k = kk*32+lg*8)
  bf16x8 aq[4][2];
#pragma unroll
  for (int mf = 0; mf < 4; ++mf)
#pragma unroll
    for (int kk = 0; kk < 2; ++kk)
      aq[mf][kk] = *(const bf16x8*)(qb + base + (size_t)(qr0 + mf * 16 + l15) * 64 +
                                    kk * 32 + lg * 8);

  // staging: each thread 4 x gload16 per iter (K s0, K s1, V s0, V s1)
  const int e = tid * 8;            // elem in 4096-elem tile
  const int row = e >> 6;           // 0..63
  const int esw = e ^ ((row & 7) << 3);  // inverse-swizzled source col group

#define ASTAGE(buf, i_)                                                            \
  {                                                                                \
    int kt0 = 2 * (i_);                                                            \
    gload16(kb + base + (size_t)kt0 * 4096 + esw, &lds[(buf) * 8192 + e]);         \
    gload16(kb + base + (size_t)(kt0 + 1) * 4096 + esw,                            \
            &lds[(buf) * 8192 + 4096 + e]);                                        \
    gload16(vb + base + (size_t)row * 1024 + kt0 * 64 + (esw & 63),                \
            &lds[16384 + (buf) * 8192 + e]);                                       \
    gload16(vb + base + (size_t)row * 1024 + (kt0 + 1) * 64 + (esw & 63),          \
            &lds[16384 + (buf) * 8192 + 4096 + e]);                                \
  }

  f32x4 o[4][4] = {};
  unsigned short* Sb = &lds[32768 + wid * 4096];

  const int niter = 2 * byq + 2;
  ASTAGE(0, 0);
  asm volatile("s_waitcnt vmcnt(0)" ::: "memory");
  __builtin_amdgcn_s_barrier();

  for (int i = 0; i < niter; ++i) {
    const int cur = i & 1;
    if (i + 1 < niter) ASTAGE(cur ^ 1, i + 1);
    const int kt = 2 * i + ks;
    if (kt <= Q) {
      const unsigned short* Kb = &lds[cur * 8192 + ks * 4096];
      const unsigned short* Vb = &lds[16384 + cur * 8192 + ks * 4096];
      // S = Q @ K^T
      bf16x8 bk[4][2];
#pragma unroll
      for (int nf = 0; nf < 4; ++nf)
#pragma unroll
        for (int kk = 0; kk < 2; ++kk)
          bk[nf][kk] = readfrag(Kb, nf * 16 + l15, kk * 64 + lg * 16);
      f32x4 s[4][4] = {};
      __builtin_amdgcn_s_setprio(1);
#pragma unroll
      for (int mf = 0; mf < 4; ++mf)
#pragma unroll
        for (int nf = 0; nf < 4; ++nf)
#pragma unroll
          for (int kk = 0; kk < 2; ++kk)
            s[mf][nf] = MFMA(aq[mf][kk], bk[nf][kk], s[mf][nf]);
      __builtin_amdgcn_s_setprio(0);
      // scale * relu * (diag) mask -> bf16 into wave-private S (swizzled)
      const bool diag = (kt == Q);
#pragma unroll
      for (int mf = 0; mf < 4; ++mf)
#pragma unroll
        for (int nf = 0; nf < 4; ++nf) {
          int colk = nf * 16 + l15;
#pragma unroll
          for (int r = 0; r < 4; ++r) {
            int rowq = mf * 16 + lg * 4 + r;
            float v = fmaxf(s[mf][nf][r] * 0.125f, 0.0f);
            if (diag && colk > rowq) v = 0.0f;
            int byte = (rowq * 128 + colk * 2) ^ ((rowq & 7) << 4);
            *(unsigned short*)((char*)Sb + byte) = f2bf(v);
          }
        }
      // O += S @ V   (wave-private: compiler orders via lgkmcnt, no barrier)
      bf16x8 pa[4][2];
#pragma unroll
      for (int mf = 0; mf < 4; ++mf)
#pragma unroll
        for (int kk = 0; kk < 2; ++kk)
          pa[mf][kk] = readfrag(Sb, mf * 16 + l15, kk * 64 + lg * 16);
      __builtin_amdgcn_s_setprio(1);
#pragma unroll
      for (int mf = 0; mf < 4; ++mf)
#pragma unroll
        for (int df = 0; df < 4; ++df)
#pragma unroll
          for (int kk = 0; kk < 2; ++kk)
            o[mf][df] = MFMA(pa[mf][kk], readfrag(Vb, df * 16 + l15, kk * 64 + lg * 16),
                             o[mf][df]);
      __builtin_amdgcn_s_setprio(0);
    }
    asm volatile("s_waitcnt vmcnt(0)" ::: "memory");
    __builtin_amdgcn_sched_barrier(0);
    __builtin_amdgcn_s_barrier();
  }
#undef ASTAGE

  // k-stream reduce: ks=1 writes O to LDS f32 (reuse K/V area), ks=0 adds+stores
  float* fr = (float*)lds;  // 4 regions x [64][64] f32 = 64KB
  if (ks == 1) {
#pragma unroll
    for (int mf = 0; mf < 4; ++mf)
#pragma unroll
      for (int df = 0; df < 4; ++df)
#pragma unroll
        for (int r = 0; r < 4; ++r) {
          int rowq = mf * 16 + lg * 4 + r, col = df * 16 + l15;
          int idx = (qs * 4096 + rowq * 64 + col) ^ ((rowq & 4) << 2);
          fr[idx] = o[mf][df][r];
        }
  }
  __syncthreads();
  if (ks == 0) {
#pragma unroll
    for (int mf = 0; mf < 4; ++mf)
#pragma unroll
      for (int df = 0; df < 4; ++df)
#pragma unroll
        for (int r = 0; r < 4; ++r) {
          int rowq = mf * 16 + lg * 4 + r, col = df * 16 + l15;
          int idx = (qs * 4096 + rowq * 64 + col) ^ ((rowq & 4) << 2);
          float v = o[mf][df][r] + fr[idx];
          out[(size_t)(b * 1024 + qr0 + rowq) * 768 + h * 64 + col] = v;
        }
  }
}

// ---- launch ----------------------------------------------------------------
extern "C" void kernel_launch(void* const* d_in, const int* in_sizes, int n_in,
                              void* d_out, int out_size, void* d_ws, size_t ws_size,
                              hipStream_t stream) {
  const float* x = (const float*)d_in[0];
  const float* W = (const float*)d_in[1];
  const float* bias = (const float*)d_in[2];
  float* out = (float*)d_out;

  unsigned short* xb = (unsigned short*)d_ws;  // 6291456 elems
  unsigned short* wt = xb + 6291456;           // 1769472 (Wt [2304][768])
  unsigned short* qb = wt + 1769472;           // [B,H,T,64]
  unsigned short* kb = qb + 6291456;
  unsigned short* vb = kb + 6291456;           // [B,H,64,T]

  cast_x_kernel<<<6144, 256, 0, stream>>>(x, xb, 1572864);
  castw_kernel<<<dim3(72, 24), 256, 0, stream>>>(W, wt);
  qkv_gemm_kernel<<<576, 512, 0, stream>>>(xb, wt, bias, qb, kb, vb);
  attn_kernel<<<384, 512, 0, stream>>>(qb, kb, vb, out);
}

// Round 4
// 93.702 us; speedup vs baseline: 1.2214x; 1.2214x over previous
//
#include <hip/hip_runtime.h>

// ---- types ----------------------------------------------------------------
typedef __attribute__((ext_vector_type(8))) short bf16x8;     // 8 bf16 (4 VGPR)
typedef __attribute__((ext_vector_type(4))) float f32x4;
typedef __attribute__((ext_vector_type(4))) unsigned short us4;
typedef __attribute__((ext_vector_type(8))) unsigned short us8;

#define MFMA(a, b, c) __builtin_amdgcn_mfma_f32_16x16x32_bf16((a), (b), (c), 0, 0, 0)

__device__ __forceinline__ unsigned short f2bf(float f) {
  unsigned u = __builtin_bit_cast(unsigned, f);
  u = (u + 0x7fffu + ((u >> 16) & 1u)) >> 16;  // RNE
  return (unsigned short)u;
}

__device__ __forceinline__ void gload16(const void* g, void* l) {
  __builtin_amdgcn_global_load_lds((const __attribute__((address_space(1))) void*)g,
                                   (__attribute__((address_space(3))) void*)l,
                                   16, 0, 0);
}

// 128B-row swizzled fragment read (attn): phys = byte ^ ((row&7)<<4)
__device__ __forceinline__ bf16x8 readfrag(const unsigned short* buf, int row, int kbyte) {
  int byte = row * 128 + kbyte;
  byte ^= (row & 7) << 4;
  return *(const bf16x8*)((const char*)buf + byte);
}

// 64B-row swizzled fragment read (GEMM BK=32): phys = byte ^ ((row&3)<<4)
__device__ __forceinline__ bf16x8 readfrag32(const unsigned short* buf, int row, int lg) {
  int byte = row * 64 + lg * 16;
  byte ^= (row & 3) << 4;
  return *(const bf16x8*)((const char*)buf + byte);
}

// ---- kernel 1: cast x -> bf16 (float4 vectorized) --------------------------
__global__ void cast_x_kernel(const float* __restrict__ x,
                              unsigned short* __restrict__ xb, int n4) {
  int id = blockIdx.x * blockDim.x + threadIdx.x;
  if (id >= n4) return;
  float4 v = ((const float4*)x)[id];
  us4 o = { f2bf(v.x), f2bf(v.y), f2bf(v.z), f2bf(v.w) };
  ((us4*)xb)[id] = o;
}

// ---- kernel 2: W [768][2304] -> Wt [2304][768] bf16 (tiled transpose) ------
__global__ void castw_kernel(const float* __restrict__ W,
                             unsigned short* __restrict__ Wt) {
  __shared__ unsigned short tile[32][33];
  int bn = blockIdx.x * 32;
  int bk = blockIdx.y * 32;
  int lx = threadIdx.x & 31, ly = threadIdx.x >> 5;  // 32 x 8
#pragma unroll
  for (int i = 0; i < 32; i += 8)
    tile[ly + i][lx] = f2bf(W[(bk + ly + i) * 2304 + bn + lx]);
  __syncthreads();
#pragma unroll
  for (int i = 0; i < 32; i += 8)
    Wt[(bn + ly + i) * 768 + bk + lx] = tile[lx][ly + i];
}

// ---- kernel 3: QKV GEMM ----------------------------------------------------
// BM=256 BN=128 BK=32, 4 waves (2x2), wave-tile 128x64 (0.375 KB LDS-read/MFMA).
// A/B triple-buffered (72KB LDS -> 2 blocks/CU), 2-ahead counted-vmcnt pipeline.
__global__ __launch_bounds__(256, 2) void qkv_gemm_kernel(
    const unsigned short* __restrict__ xb, const unsigned short* __restrict__ wt,
    const float* __restrict__ bias,
    unsigned short* __restrict__ qb, unsigned short* __restrict__ kb,
    unsigned short* __restrict__ vb) {
  __shared__ unsigned short lds[36864];  // A 3x8192 elems @0, B 3x4096 @24576
  const int tid = threadIdx.x;
  const int lane = tid & 63, wid = tid >> 6;
  const int wm = wid >> 1, wn = wid & 1;   // wave-tile: m 128, n 64
  const int l15 = lane & 15, lg = lane >> 4;

  int bid = blockIdx.x;
  int xcd = bid & 7, c = bid >> 3;
  int mb = (xcd & 3) * 8 + (c & 7);
  int nb = (xcd >> 2) * 9 + (c >> 3);
  const int m0 = mb * 256, n0 = nb * 128;

  const unsigned short* Ab_g = xb + (size_t)m0 * 768;
  const unsigned short* Bb_g = wt + (size_t)n0 * 768;

  // stage addressing: linear LDS dest, inverse-swizzled global source (32-elem rows)
  int eA[4], sA[4], eB[2], sB[2];
#pragma unroll
  for (int i = 0; i < 4; ++i) {
    int e = (i * 256 + tid) * 8, row = e >> 5;
    eA[i] = e;
    sA[i] = row * 768 + ((e ^ ((row & 3) << 3)) & 31);
  }
#pragma unroll
  for (int i = 0; i < 2; ++i) {
    int e = (i * 256 + tid) * 8, row = e >> 5;
    eB[i] = e;
    sB[i] = row * 768 + ((e ^ ((row & 3) << 3)) & 31);
  }

#define SA(buf, k0, i) gload16(Ab_g + sA[i] + (k0), &lds[(buf) * 8192 + eA[i]])
#define SB(buf, k0, i) gload16(Bb_g + sB[i] + (k0), &lds[24576 + (buf) * 4096 + eB[i]])

  f32x4 acc[8][4] = {};
  bf16x8 bfr[4];

  // prologue: stage t0 (6 loads) + t1 (6); wait t0 (allow newest 6)
  SA(0, 0, 0); SA(0, 0, 1); SA(0, 0, 2); SA(0, 0, 3);
  SB(0, 0, 0); SB(0, 0, 1);
  SA(1, 32, 0); SA(1, 32, 1); SA(1, 32, 2); SA(1, 32, 3);
  SB(1, 32, 0); SB(1, 32, 1);
  asm volatile("s_waitcnt vmcnt(6)" ::: "memory");
  __builtin_amdgcn_s_barrier();

// phase: ds_read quadrant -> issue stage -> barrier -> lgkmcnt(0) -> 16 MFMA -> [vmcnt] -> barrier
#define GPHASE(cc_, P, STG, EW)                                              \
  {                                                                          \
    const unsigned short* Abuf = &lds[(cc_) * 8192];                         \
    const unsigned short* Bbuf = &lds[24576 + (cc_) * 4096];                 \
    bf16x8 afr[4];                                                           \
    _Pragma("unroll") for (int m4 = 0; m4 < 4; ++m4)                         \
        afr[m4] = readfrag32(Abuf, wm * 128 + ((P) * 4 + m4) * 16 + l15, lg);\
    if ((P) == 0) {                                                          \
      _Pragma("unroll") for (int nf = 0; nf < 4; ++nf)                       \
          bfr[nf] = readfrag32(Bbuf, wn * 64 + nf * 16 + l15, lg);           \
    }                                                                        \
    STG;                                                                     \
    __builtin_amdgcn_sched_barrier(0);                                       \
    __builtin_amdgcn_s_barrier();                                            \
    asm volatile("s_waitcnt lgkmcnt(0)" ::: "memory");                       \
    __builtin_amdgcn_sched_barrier(0);                                       \
    __builtin_amdgcn_s_setprio(1);                                           \
    _Pragma("unroll") for (int m4 = 0; m4 < 4; ++m4)                         \
        _Pragma("unroll") for (int nf = 0; nf < 4; ++nf)                     \
            acc[(P) * 4 + m4][nf] = MFMA(afr[m4], bfr[nf], acc[(P) * 4 + m4][nf]); \
    __builtin_amdgcn_s_setprio(0);                                           \
    EW;                                                                      \
    __builtin_amdgcn_sched_barrier(0);                                       \
    __builtin_amdgcn_s_barrier();                                            \
  }

  // main loop: iter t consumes buf t%3, stages t+2 into (t+2)%3.
  // end-of-iter vmcnt(6): newest 6 = t+2's stages; drains t+1's.
  int cc = 0;
  for (int t = 0; t < 22; ++t) {
    int c2 = cc + 2; if (c2 >= 3) c2 -= 3;
    int k2 = (t + 2) * 32;
    GPHASE(cc, 0, { SA(c2, k2, 0); SA(c2, k2, 1); SB(c2, k2, 0); }, );
    GPHASE(cc, 1, { SA(c2, k2, 2); SA(c2, k2, 3); SB(c2, k2, 1); },
           asm volatile("s_waitcnt vmcnt(6)" ::: "memory"));
    cc = (cc == 2) ? 0 : cc + 1;
  }
  // t=22: no stage; drain everything at end
  GPHASE(cc, 0, , );
  GPHASE(cc, 1, , asm volatile("s_waitcnt vmcnt(0)" ::: "memory"));
  cc = (cc == 2) ? 0 : cc + 1;
  // t=23
  GPHASE(cc, 0, , );
  GPHASE(cc, 1, , );

  __syncthreads();  // reuse LDS for epilogue

  const int sec = n0 / 768;  // 0=q,1=k,2=v (block-uniform)
  float bcol[4];
#pragma unroll
  for (int nf = 0; nf < 4; ++nf) bcol[nf] = bias[n0 + wn * 64 + nf * 16 + l15];

  if (sec < 2) {
    unsigned short* ct = lds;  // [256][128] = 32768 elems (fits 36864)
#pragma unroll
    for (int mf = 0; mf < 8; ++mf)
#pragma unroll
      for (int nf = 0; nf < 4; ++nf)
#pragma unroll
        for (int r = 0; r < 4; ++r)
          ct[(wm * 128 + mf * 16 + lg * 4 + r) * 128 + wn * 64 + nf * 16 + l15] =
              f2bf(acc[mf][nf][r] + bcol[nf]);
    __syncthreads();
    unsigned short* dstbase = (sec == 0) ? qb : kb;
    const int hbase = (n0 - sec * 768) >> 6;
    const int g8 = tid >> 3, l8 = tid & 7;  // 32 groups x 8 lanes
#pragma unroll
    for (int j = 0; j < 16; ++j) {
      int chunk = j * 32 + g8;  // 0..511 = row*2 + hh
      int row = chunk >> 1, hh = chunk & 1;
      us8 v = *(const us8*)&ct[row * 128 + hh * 64 + l8 * 8];
      int t = m0 + row, bb = t >> 10, tt = t & 1023;
      *(us8*)(dstbase + ((size_t)((bb * 12 + hbase + hh) * 1024 + tt)) * 64 + l8 * 8) = v;
    }
  } else {
    // v transposed [B,H,64,T]: us4 stores along t
#pragma unroll
    for (int nf = 0; nf < 4; ++nf) {
      int cc2 = (n0 - 1536) + wn * 64 + nf * 16 + l15;
      int h = cc2 >> 6, d = cc2 & 63;
#pragma unroll
      for (int mf = 0; mf < 8; ++mf) {
        int row0 = m0 + wm * 128 + mf * 16 + lg * 4;
        int bb = row0 >> 10, t0 = row0 & 1023;
        us4 o;
#pragma unroll
        for (int r = 0; r < 4; ++r) o[r] = f2bf(acc[mf][nf][r] + bcol[nf]);
        *(us4*)(vb + ((size_t)((bb * 12 + h) * 64 + d)) * 1024 + t0) = o;
      }
    }
  }
#undef SA
#undef SB
#undef GPHASE
}

// ---- kernel 4: causal ReLU attention, GEMM-shaped --------------------------
// block = (b,h) x 256 q-rows. 8 waves = 4 q-subtiles x 2 k-streams.
// (512,2): VGPR cap 256 -> no scratch spill (R3's 128-cap spilled ~13MB/dispatch).
__global__ __launch_bounds__(512, 2) void attn_kernel(
    const unsigned short* __restrict__ qb, const unsigned short* __restrict__ kb,
    const unsigned short* __restrict__ vb, float* __restrict__ out) {
  // LDS elems: K [buf][stream][4096] @0..16384, V @16384..32768,
  //            S per-wave 4096 @32768+wid*4096. Total 65536 elems = 128KB.
  __shared__ unsigned short lds[65536];
  const int tid = threadIdx.x;
  const int lane = tid & 63, wid = tid >> 6;
  const int qs = wid >> 1, ks = wid & 1;
  const int l15 = lane & 15, lg = lane >> 4;

  int bid = blockIdx.x;
  int xcd = bid & 7, c = bid >> 3;       // c 0..47
  int bh = xcd * 12 + (c % 12);
  int byq = 3 - (c / 12);                // heavy q-blocks first
  const int b = bh / 12, h = bh % 12;
  const size_t base = (size_t)bh * 65536;
  const int Q = byq * 4 + qs;
  const int qr0 = byq * 256 + qs * 64;

  bf16x8 aq[4][2];
#pragma unroll
  for (int mf = 0; mf < 4; ++mf)
#pragma unroll
    for (int kk = 0; kk < 2; ++kk)
      aq[mf][kk] = *(const bf16x8*)(qb + base + (size_t)(qr0 + mf * 16 + l15) * 64 +
                                    kk * 32 + lg * 8);

  const int e = tid * 8;
  const int row = e >> 6;
  const int esw = e ^ ((row & 7) << 3);

#define ASTAGE(buf, i_)                                                            \
  {                                                                                \
    int kt0 = 2 * (i_);                                                            \
    gload16(kb + base + (size_t)kt0 * 4096 + esw, &lds[(buf) * 8192 + e]);         \
    gload16(kb + base + (size_t)(kt0 + 1) * 4096 + esw,                            \
            &lds[(buf) * 8192 + 4096 + e]);                                        \
    gload16(vb + base + (size_t)row * 1024 + kt0 * 64 + (esw & 63),                \
            &lds[16384 + (buf) * 8192 + e]);                                       \
    gload16(vb + base + (size_t)row * 1024 + (kt0 + 1) * 64 + (esw & 63),          \
            &lds[16384 + (buf) * 8192 + 4096 + e]);                                \
  }

  f32x4 o[4][4] = {};
  unsigned short* Sb = &lds[32768 + wid * 4096];

  const int niter = 2 * byq + 2;
  ASTAGE(0, 0);
  asm volatile("s_waitcnt vmcnt(0)" ::: "memory");
  __builtin_amdgcn_s_barrier();

  for (int i = 0; i < niter; ++i) {
    const int cur = i & 1;
    if (i + 1 < niter) ASTAGE(cur ^ 1, i + 1);
    const int kt = 2 * i + ks;
    if (kt <= Q) {
      const unsigned short* Kb = &lds[cur * 8192 + ks * 4096];
      const unsigned short* Vb = &lds[16384 + cur * 8192 + ks * 4096];
      bf16x8 bk[4][2];
#pragma unroll
      for (int nf = 0; nf < 4; ++nf)
#pragma unroll
        for (int kk = 0; kk < 2; ++kk)
          bk[nf][kk] = readfrag(Kb, nf * 16 + l15, kk * 64 + lg * 16);
      const bool diag = (kt == Q);
      // per-tile S: compute 2 MFMA -> mask -> cvt -> LDS; keeps live f32 small
      __builtin_amdgcn_s_setprio(1);
#pragma unroll
      for (int mf = 0; mf < 4; ++mf)
#pragma unroll
        for (int nf = 0; nf < 4; ++nf) {
          f32x4 s = {};
          s = MFMA(aq[mf][0], bk[nf][0], s);
          s = MFMA(aq[mf][1], bk[nf][1], s);
          int colk = nf * 16 + l15;
#pragma unroll
          for (int r = 0; r < 4; ++r) {
            int rowq = mf * 16 + lg * 4 + r;
            float v = fmaxf(s[r] * 0.125f, 0.0f);
            if (diag && colk > rowq) v = 0.0f;
            int byte = (rowq * 128 + colk * 2) ^ ((rowq & 7) << 4);
            *(unsigned short*)((char*)Sb + byte) = f2bf(v);
          }
        }
      __builtin_amdgcn_s_setprio(0);
      // O += S @ V (wave-private S; compiler orders via lgkmcnt)
      bf16x8 pa[4][2];
#pragma unroll
      for (int mf = 0; mf < 4; ++mf)
#pragma unroll
        for (int kk = 0; kk < 2; ++kk)
          pa[mf][kk] = readfrag(Sb, mf * 16 + l15, kk * 64 + lg * 16);
      __builtin_amdgcn_s_setprio(1);
#pragma unroll
      for (int mf = 0; mf < 4; ++mf)
#pragma unroll
        for (int df = 0; df < 4; ++df)
#pragma unroll
          for (int kk = 0; kk < 2; ++kk)
            o[mf][df] = MFMA(pa[mf][kk], readfrag(Vb, df * 16 + l15, kk * 64 + lg * 16),
                             o[mf][df]);
      __builtin_amdgcn_s_setprio(0);
    }
    asm volatile("s_waitcnt vmcnt(0)" ::: "memory");
    __builtin_amdgcn_sched_barrier(0);
    __builtin_amdgcn_s_barrier();
  }
#undef ASTAGE

  // k-stream reduce: ks=1 writes O to LDS f32 (reuse K/V area), ks=0 adds+stores
  float* fr = (float*)lds;
  if (ks == 1) {
#pragma unroll
    for (int mf = 0; mf < 4; ++mf)
#pragma unroll
      for (int df = 0; df < 4; ++df)
#pragma unroll
        for (int r = 0; r < 4; ++r) {
          int rowq = mf * 16 + lg * 4 + r, col = df * 16 + l15;
          int idx = (qs * 4096 + rowq * 64 + col) ^ ((rowq & 4) << 2);
          fr[idx] = o[mf][df][r];
        }
  }
  __syncthreads();
  if (ks == 0) {
#pragma unroll
    for (int mf = 0; mf < 4; ++mf)
#pragma unroll
      for (int df = 0; df < 4; ++df)
#pragma unroll
        for (int r = 0; r < 4; ++r) {
          int rowq = mf * 16 + lg * 4 + r, col = df * 16 + l15;
          int idx = (qs * 4096 + rowq * 64 + col) ^ ((rowq & 4) << 2);
          float v = o[mf][df][r] + fr[idx];
          out[(size_t)(b * 1024 + qr0 + rowq) * 768 + h * 64 + col] = v;
        }
  }
}

// ---- launch ----------------------------------------------------------------
extern "C" void kernel_launch(void* const* d_in, const int* in_sizes, int n_in,
                              void* d_out, int out_size, void* d_ws, size_t ws_size,
                              hipStream_t stream) {
  const float* x = (const float*)d_in[0];
  const float* W = (const float*)d_in[1];
  const float* bias = (const float*)d_in[2];
  float* out = (float*)d_out;

  unsigned short* xb = (unsigned short*)d_ws;  // 6291456 elems
  unsigned short* wt = xb + 6291456;           // 1769472 (Wt [2304][768])
  unsigned short* qb = wt + 1769472;           // [B,H,T,64]
  unsigned short* kb = qb + 6291456;
  unsigned short* vb = kb + 6291456;           // [B,H,64,T]

  cast_x_kernel<<<6144, 256, 0, stream>>>(x, xb, 1572864);
  castw_kernel<<<dim3(72, 24), 256, 0, stream>>>(W, wt);
  qkv_gemm_kernel<<<576, 256, 0, stream>>>(xb, wt, bias, qb, kb, vb);
  attn_kernel<<<384, 512, 0, stream>>>(qb, kb, vb, out);
}